// Round 2
// baseline (297.841 us; speedup 1.0000x reference)
//
#include <hip/hip_runtime.h>
#include <hip/hip_bf16.h>

#define EMB 512
#define RD  64
#define NB  8
#define K1  2048
#define K2  2048

typedef short bf16x8 __attribute__((ext_vector_type(8)));  // 8 bf16 = 4 VGPRs (guide §3)
typedef float f32x4  __attribute__((ext_vector_type(4)));

// emb_scale = 1/sqrt(512); red_scale = 1/8 folded into ra
#define SCALE_B 0.04419417382415922f
#define SCALE_A 0.005524271728019902f

// ---------------------------------------------------------------------------
// Kernel 1: project embeddings through R (fp32), store bf16 ra/rb + zero mask.
// Block = 256 thr (4 waves). Block handles 32 rows of the 32768-row concat
// [A(16384) | B(16384)]. 32x512 fp32 tile staged in LDS (64 KB), lane = col.
// ---------------------------------------------------------------------------
__global__ __launch_bounds__(256) void k_project(
    const float* __restrict__ A, const float* __restrict__ Bm,
    const float* __restrict__ R,
    __hip_bfloat16* __restrict__ ra, __hip_bfloat16* __restrict__ rb,
    unsigned char* __restrict__ mask)
{
  __shared__ float lds[32 * EMB];   // 64 KB
  const int t   = threadIdx.x;
  const int blk = blockIdx.x;                 // 0..1023; >=512 -> B half
  const bool isB = blk >= 512;
  const float* __restrict__ src = isB ? Bm : A;
  const int rowstart = (isB ? blk - 512 : blk) * 32;   // row within 16384-row half

  // stage 32x512 floats, coalesced float4
  const float4* s4 = reinterpret_cast<const float4*>(src + (size_t)rowstart * EMB);
  float4* l4 = reinterpret_cast<float4*>(lds);
  #pragma unroll
  for (int i = 0; i < 16; ++i) l4[i * 256 + t] = s4[i * 256 + t];
  __syncthreads();

  const int w = t >> 6, lane = t & 63;        // lane = output col (RD==64)
  float acc[8];
  float nzm[8];
  #pragma unroll
  for (int r = 0; r < 8; ++r) { acc[r] = 0.f; nzm[r] = 0.f; }

  if (!isB) {
    for (int k0 = 0; k0 < EMB; k0 += 4) {
      float q0 = R[(size_t)(k0 + 0) * RD + lane];
      float q1 = R[(size_t)(k0 + 1) * RD + lane];
      float q2 = R[(size_t)(k0 + 2) * RD + lane];
      float q3 = R[(size_t)(k0 + 3) * RD + lane];
      #pragma unroll
      for (int r = 0; r < 8; ++r) {
        float4 a = *reinterpret_cast<const float4*>(&lds[(w * 8 + r) * EMB + k0]);
        acc[r] = fmaf(a.x, q0, fmaf(a.y, q1, fmaf(a.z, q2, fmaf(a.w, q3, acc[r]))));
      }
    }
  } else {
    for (int k0 = 0; k0 < EMB; k0 += 4) {
      float q0 = R[(size_t)(k0 + 0) * RD + lane];
      float q1 = R[(size_t)(k0 + 1) * RD + lane];
      float q2 = R[(size_t)(k0 + 2) * RD + lane];
      float q3 = R[(size_t)(k0 + 3) * RD + lane];
      #pragma unroll
      for (int r = 0; r < 8; ++r) {
        float4 a = *reinterpret_cast<const float4*>(&lds[(w * 8 + r) * EMB + k0]);
        acc[r] = fmaf(a.x, q0, fmaf(a.y, q1, fmaf(a.z, q2, fmaf(a.w, q3, acc[r]))));
        // zero-row detection: every lane sees the whole row (uniform reads)
        float m3 = fmaxf(fmaxf(fabsf(a.x), fabsf(a.y)), fabsf(a.z));
        nzm[r] = fmaxf(nzm[r], fmaxf(m3, fabsf(a.w)));
      }
    }
  }

  const float scale = isB ? SCALE_B : SCALE_A;
  __hip_bfloat16* __restrict__ dst = isB ? rb : ra;
  #pragma unroll
  for (int r = 0; r < 8; ++r)
    dst[(size_t)(rowstart + w * 8 + r) * RD + lane] = __float2bfloat16(acc[r] * scale);

  if (isB && lane == 0) {
    #pragma unroll
    for (int r = 0; r < 8; ++r)
      mask[rowstart + w * 8 + r] = (nzm[r] == 0.f) ? 1 : 0;
  }
}

// ---------------------------------------------------------------------------
// Kernel 2: fused scores GEMM (bf16 MFMA, NT) + mask + bias + row softmax.
// Block = 256 thr (4 waves) handles 16 rows x 2048 cols of one batch.
// Pass 1: online sum of exp(s).  Pass 2: recompute (rb L2-hot), write p.
// scores ~ -3 +/- 0.003 -> exp(s) directly, no max subtraction needed.
// ---------------------------------------------------------------------------
__global__ __launch_bounds__(256) void k_scores(
    const __hip_bfloat16* __restrict__ ra, const __hip_bfloat16* __restrict__ rb,
    const unsigned char* __restrict__ mask, const float* __restrict__ bptr,
    float* __restrict__ out)
{
  const int bz = blockIdx.y;
  const int row_base = blockIdx.x * 16;
  const int w = threadIdx.x >> 6, lane = threadIdx.x & 63;
  const int m = lane & 15, quad = lane >> 4;
  const float bias = bptr[0];

  const __hip_bfloat16* __restrict__ raB = ra + ((size_t)bz * K1 + row_base) * RD;
  const __hip_bfloat16* __restrict__ rbB = rb + (size_t)bz * K2 * RD;
  const unsigned char* __restrict__ mk = mask + bz * K2;

  // A frags: lane holds A[m=lane&15][k = quad*8 + j]  (two K=32 slabs)
  bf16x8 a0 = *reinterpret_cast<const bf16x8*>(raB + m * RD + quad * 8);
  bf16x8 a1 = *reinterpret_cast<const bf16x8*>(raB + m * RD + 32 + quad * 8);

  float sums[4] = {0.f, 0.f, 0.f, 0.f};

  // ---- pass 1: sum of exp per row ----
  for (int tle = w; tle < K2 / 16; tle += 4) {
    const int n = tle * 16 + m;
    bf16x8 b0 = *reinterpret_cast<const bf16x8*>(rbB + n * RD + quad * 8);
    bf16x8 b1 = *reinterpret_cast<const bf16x8*>(rbB + n * RD + 32 + quad * 8);
    f32x4 c = {0.f, 0.f, 0.f, 0.f};
    c = __builtin_amdgcn_mfma_f32_16x16x32_bf16(a0, b0, c, 0, 0, 0);
    c = __builtin_amdgcn_mfma_f32_16x16x32_bf16(a1, b1, c, 0, 0, 0);
    const bool msk = mk[n] != 0;
    #pragma unroll
    for (int i = 0; i < 4; ++i) {
      float e = msk ? 0.f : __expf(c[i] + bias);   // C/D: col=lane&15, row=quad*4+i
      sums[i] += e;
    }
  }

  // reduce over the 16 lanes (col dimension) of each quad
  #pragma unroll
  for (int i = 0; i < 4; ++i) {
    float v = sums[i];
    v += __shfl_xor(v, 1);
    v += __shfl_xor(v, 2);
    v += __shfl_xor(v, 4);
    v += __shfl_xor(v, 8);
    sums[i] = v;
  }

  __shared__ float partial[4][16];
  __shared__ float rowinv[16];
  if ((lane & 15) == 0) {
    #pragma unroll
    for (int i = 0; i < 4; ++i) partial[w][quad * 4 + i] = sums[i];
  }
  __syncthreads();
  if (threadIdx.x < 16) {
    float tsum = partial[0][threadIdx.x] + partial[1][threadIdx.x] +
                 partial[2][threadIdx.x] + partial[3][threadIdx.x];
    rowinv[threadIdx.x] = 1.0f / tsum;
  }
  __syncthreads();

  float inv[4];
  #pragma unroll
  for (int i = 0; i < 4; ++i) inv[i] = rowinv[quad * 4 + i];

  // ---- pass 2: recompute and write p = exp(s) * inv ----
  float* __restrict__ outB = out + ((size_t)bz * K1 + row_base) * K2;
  for (int tle = w; tle < K2 / 16; tle += 4) {
    const int n = tle * 16 + m;
    bf16x8 b0 = *reinterpret_cast<const bf16x8*>(rbB + n * RD + quad * 8);
    bf16x8 b1 = *reinterpret_cast<const bf16x8*>(rbB + n * RD + 32 + quad * 8);
    f32x4 c = {0.f, 0.f, 0.f, 0.f};
    c = __builtin_amdgcn_mfma_f32_16x16x32_bf16(a0, b0, c, 0, 0, 0);
    c = __builtin_amdgcn_mfma_f32_16x16x32_bf16(a1, b1, c, 0, 0, 0);
    const bool msk = mk[n] != 0;
    #pragma unroll
    for (int i = 0; i < 4; ++i) {
      float e = msk ? 0.f : __expf(c[i] + bias);
      outB[(size_t)(quad * 4 + i) * K2 + n] = e * inv[i];
    }
  }
}

extern "C" void kernel_launch(void* const* d_in, const int* in_sizes, int n_in,
                              void* d_out, int out_size, void* d_ws, size_t ws_size,
                              hipStream_t stream) {
  const float* A  = (const float*)d_in[0];   // (8, 2048, 512)
  const float* Bm = (const float*)d_in[1];   // (8, 2048, 512)
  const float* R  = (const float*)d_in[2];   // (512, 64)
  const float* bb = (const float*)d_in[3];   // (1,)
  float* out = (float*)d_out;                // (8, 2048, 2048)

  char* ws = (char*)d_ws;
  __hip_bfloat16* ra  = (__hip_bfloat16*)(ws);                       // 2 MB
  __hip_bfloat16* rb  = (__hip_bfloat16*)(ws + (((size_t)2) << 20)); // 2 MB
  unsigned char*  msk = (unsigned char*) (ws + (((size_t)4) << 20)); // 16 KB

  k_project<<<dim3(1024), dim3(256), 0, stream>>>(A, Bm, R, ra, rb, msk);
  k_scores <<<dim3(K1 / 16, NB), dim3(256), 0, stream>>>(ra, rb, msk, bb, out);
}

// Round 3
// 247.743 us; speedup vs baseline: 1.2022x; 1.2022x over previous
//
#include <hip/hip_runtime.h>
#include <hip/hip_bf16.h>

#define EMB 512
#define RD  64
#define NB  8
#define K1  2048
#define K2  2048

typedef short bf16x8 __attribute__((ext_vector_type(8)));  // 8 bf16 = 4 VGPRs
typedef float f32x4  __attribute__((ext_vector_type(4)));

// emb_scale = 1/sqrt(512); red_scale = 1/8 folded into ra
#define SCALE_B 0.04419417382415922f
#define SCALE_A 0.005524271728019902f

// ---------------------------------------------------------------------------
// Kernel 0: Rt[n][k] = bf16(R[k][n])  (64 x 512, 64 KB) — B-operand wants
// n-major / k-contiguous layout (validated by k_scores frag mapping).
// ---------------------------------------------------------------------------
__global__ __launch_bounds__(256) void k_prep_rt(
    const float* __restrict__ R, __hip_bfloat16* __restrict__ Rt)
{
  int idx = blockIdx.x * 256 + threadIdx.x;   // 32768 total
  int k = idx >> 6, n = idx & 63;             // coalesced read of R[k][n]
  Rt[(size_t)n * EMB + k] = __float2bfloat16(R[idx]);
}

// ---------------------------------------------------------------------------
// Kernel 1: projection via bf16 MFMA, no LDS.
// Wave = 16 rows x 64 cols, K=512 in 16 steps of 32.
// A-frag: lane reads X[rowbase + (lane&15)][kk + quad*8 .. +8] fp32 -> bf16.
// B-frag: Rt[nt*16 + (lane&15)][kk + quad*8 .. +8]  (L1/L2-hot).
// C/D: col = lane&15, row = quad*4 + i.
// Mask (B half): per-lane fp32 |x| max over its 128 elems, shfl_xor(16,32).
// ---------------------------------------------------------------------------
__global__ __launch_bounds__(256) void k_project(
    const float* __restrict__ A, const float* __restrict__ Bm,
    const __hip_bfloat16* __restrict__ Rt,
    __hip_bfloat16* __restrict__ ra, __hip_bfloat16* __restrict__ rb,
    unsigned char* __restrict__ mask)
{
  const int t = threadIdx.x;
  const int w = t >> 6, lane = t & 63;
  const int m = lane & 15, quad = lane >> 4;
  const int blk = blockIdx.x;                 // 0..511; >=256 -> B half
  const bool isB = blk >= 256;
  const float* __restrict__ src = isB ? Bm : A;
  const int rowbase = ((isB ? blk - 256 : blk) * 4 + w) * 16;  // 16 rows / wave
  const float* __restrict__ xrow = src + (size_t)(rowbase + m) * EMB;

  f32x4 acc[4] = {{0.f,0.f,0.f,0.f},{0.f,0.f,0.f,0.f},
                  {0.f,0.f,0.f,0.f},{0.f,0.f,0.f,0.f}};
  float nzm = 0.f;

  #pragma unroll
  for (int kk = 0; kk < EMB; kk += 32) {
    float4 x0 = *reinterpret_cast<const float4*>(xrow + kk + quad * 8);
    float4 x1 = *reinterpret_cast<const float4*>(xrow + kk + quad * 8 + 4);

    nzm = fmaxf(nzm, fmaxf(fmaxf(fabsf(x0.x), fabsf(x0.y)),
                           fmaxf(fabsf(x0.z), fabsf(x0.w))));
    nzm = fmaxf(nzm, fmaxf(fmaxf(fabsf(x1.x), fabsf(x1.y)),
                           fmaxf(fabsf(x1.z), fabsf(x1.w))));

    union { bf16x8 v; __hip_bfloat16 h[8]; } af;
    af.h[0] = __float2bfloat16(x0.x); af.h[1] = __float2bfloat16(x0.y);
    af.h[2] = __float2bfloat16(x0.z); af.h[3] = __float2bfloat16(x0.w);
    af.h[4] = __float2bfloat16(x1.x); af.h[5] = __float2bfloat16(x1.y);
    af.h[6] = __float2bfloat16(x1.z); af.h[7] = __float2bfloat16(x1.w);

    #pragma unroll
    for (int nt = 0; nt < 4; ++nt) {
      bf16x8 bf = *reinterpret_cast<const bf16x8*>(
          Rt + (size_t)(nt * 16 + m) * EMB + kk + quad * 8);
      acc[nt] = __builtin_amdgcn_mfma_f32_16x16x32_bf16(af.v, bf, acc[nt], 0, 0, 0);
    }
  }

  const float scale = isB ? SCALE_B : SCALE_A;
  __hip_bfloat16* __restrict__ dst = isB ? rb : ra;
  #pragma unroll
  for (int nt = 0; nt < 4; ++nt) {
    #pragma unroll
    for (int i = 0; i < 4; ++i) {
      const int r = rowbase + quad * 4 + i;          // C/D row = quad*4+i
      dst[(size_t)r * RD + nt * 16 + m] = __float2bfloat16(acc[nt][i] * scale);
    }
  }

  // mask: rows rowbase..rowbase+15; lanes sharing m hold partial maxes
  float v = nzm;
  v = fmaxf(v, __shfl_xor(v, 16));
  v = fmaxf(v, __shfl_xor(v, 32));
  if (isB && lane < 16)
    mask[rowbase + lane] = (v == 0.f) ? 1 : 0;
}

// ---------------------------------------------------------------------------
// Kernel 2: fused scores GEMM (bf16 MFMA, NT) + mask + bias + row softmax.
// (unchanged from R2 — isolating the k_project change)
// ---------------------------------------------------------------------------
__global__ __launch_bounds__(256) void k_scores(
    const __hip_bfloat16* __restrict__ ra, const __hip_bfloat16* __restrict__ rb,
    const unsigned char* __restrict__ mask, const float* __restrict__ bptr,
    float* __restrict__ out)
{
  const int bz = blockIdx.y;
  const int row_base = blockIdx.x * 16;
  const int w = threadIdx.x >> 6, lane = threadIdx.x & 63;
  const int m = lane & 15, quad = lane >> 4;
  const float bias = bptr[0];

  const __hip_bfloat16* __restrict__ raB = ra + ((size_t)bz * K1 + row_base) * RD;
  const __hip_bfloat16* __restrict__ rbB = rb + (size_t)bz * K2 * RD;
  const unsigned char* __restrict__ mk = mask + bz * K2;

  bf16x8 a0 = *reinterpret_cast<const bf16x8*>(raB + m * RD + quad * 8);
  bf16x8 a1 = *reinterpret_cast<const bf16x8*>(raB + m * RD + 32 + quad * 8);

  float sums[4] = {0.f, 0.f, 0.f, 0.f};

  // ---- pass 1: sum of exp per row ----
  for (int tle = w; tle < K2 / 16; tle += 4) {
    const int n = tle * 16 + m;
    bf16x8 b0 = *reinterpret_cast<const bf16x8*>(rbB + n * RD + quad * 8);
    bf16x8 b1 = *reinterpret_cast<const bf16x8*>(rbB + n * RD + 32 + quad * 8);
    f32x4 c = {0.f, 0.f, 0.f, 0.f};
    c = __builtin_amdgcn_mfma_f32_16x16x32_bf16(a0, b0, c, 0, 0, 0);
    c = __builtin_amdgcn_mfma_f32_16x16x32_bf16(a1, b1, c, 0, 0, 0);
    const bool msk = mk[n] != 0;
    #pragma unroll
    for (int i = 0; i < 4; ++i) {
      float e = msk ? 0.f : __expf(c[i] + bias);
      sums[i] += e;
    }
  }

  #pragma unroll
  for (int i = 0; i < 4; ++i) {
    float v = sums[i];
    v += __shfl_xor(v, 1);
    v += __shfl_xor(v, 2);
    v += __shfl_xor(v, 4);
    v += __shfl_xor(v, 8);
    sums[i] = v;
  }

  __shared__ float partial[4][16];
  __shared__ float rowinv[16];
  if ((lane & 15) == 0) {
    #pragma unroll
    for (int i = 0; i < 4; ++i) partial[w][quad * 4 + i] = sums[i];
  }
  __syncthreads();
  if (threadIdx.x < 16) {
    float tsum = partial[0][threadIdx.x] + partial[1][threadIdx.x] +
                 partial[2][threadIdx.x] + partial[3][threadIdx.x];
    rowinv[threadIdx.x] = 1.0f / tsum;
  }
  __syncthreads();

  float inv[4];
  #pragma unroll
  for (int i = 0; i < 4; ++i) inv[i] = rowinv[quad * 4 + i];

  // ---- pass 2: recompute and write p = exp(s) * inv ----
  float* __restrict__ outB = out + ((size_t)bz * K1 + row_base) * K2;
  for (int tle = w; tle < K2 / 16; tle += 4) {
    const int n = tle * 16 + m;
    bf16x8 b0 = *reinterpret_cast<const bf16x8*>(rbB + n * RD + quad * 8);
    bf16x8 b1 = *reinterpret_cast<const bf16x8*>(rbB + n * RD + 32 + quad * 8);
    f32x4 c = {0.f, 0.f, 0.f, 0.f};
    c = __builtin_amdgcn_mfma_f32_16x16x32_bf16(a0, b0, c, 0, 0, 0);
    c = __builtin_amdgcn_mfma_f32_16x16x32_bf16(a1, b1, c, 0, 0, 0);
    const bool msk = mk[n] != 0;
    #pragma unroll
    for (int i = 0; i < 4; ++i) {
      float e = msk ? 0.f : __expf(c[i] + bias);
      outB[(size_t)(quad * 4 + i) * K2 + n] = e * inv[i];
    }
  }
}

extern "C" void kernel_launch(void* const* d_in, const int* in_sizes, int n_in,
                              void* d_out, int out_size, void* d_ws, size_t ws_size,
                              hipStream_t stream) {
  const float* A  = (const float*)d_in[0];   // (8, 2048, 512)
  const float* Bm = (const float*)d_in[1];   // (8, 2048, 512)
  const float* R  = (const float*)d_in[2];   // (512, 64)
  const float* bb = (const float*)d_in[3];   // (1,)
  float* out = (float*)d_out;                // (8, 2048, 2048)

  char* ws = (char*)d_ws;
  __hip_bfloat16* ra  = (__hip_bfloat16*)(ws);                         // 2 MB
  __hip_bfloat16* rb  = (__hip_bfloat16*)(ws + (((size_t)2) << 20));   // 2 MB
  __hip_bfloat16* Rt  = (__hip_bfloat16*)(ws + (((size_t)4) << 20));   // 64 KB
  unsigned char*  msk = (unsigned char*) (ws + (((size_t)4) << 20) + 65536); // 16 KB

  k_prep_rt<<<dim3(128), dim3(256), 0, stream>>>(R, Rt);
  k_project<<<dim3(512), dim3(256), 0, stream>>>(A, Bm, Rt, ra, rb, msk);
  k_scores <<<dim3(K1 / 16, NB), dim3(256), 0, stream>>>(ra, rb, msk, bb, out);
}

// Round 4
// 241.400 us; speedup vs baseline: 1.2338x; 1.0263x over previous
//
#include <hip/hip_runtime.h>
#include <hip/hip_bf16.h>

#define EMB 512
#define RD  64
#define NB  8
#define K1  2048
#define K2  2048

typedef short bf16x8 __attribute__((ext_vector_type(8)));  // 8 bf16 = 4 VGPRs
typedef float f32x4  __attribute__((ext_vector_type(4)));

// emb_scale = 1/sqrt(512); red_scale = 1/8 folded into ra
#define SCALE_B 0.04419417382415922f
#define SCALE_A 0.005524271728019902f

// ---------------------------------------------------------------------------
// Kernel 0: Rt[n][k] = bf16(R[k][n])  (64 x 512, 64 KB) — B-operand layout.
// ---------------------------------------------------------------------------
__global__ __launch_bounds__(256) void k_prep_rt(
    const float* __restrict__ R, __hip_bfloat16* __restrict__ Rt)
{
  int idx = blockIdx.x * 256 + threadIdx.x;   // 32768 total
  int k = idx >> 6, n = idx & 63;             // coalesced read of R[k][n]
  Rt[(size_t)n * EMB + k] = __float2bfloat16(R[idx]);
}

// ---------------------------------------------------------------------------
// Kernel 1: projection via bf16 MFMA, no LDS.  (unchanged from R3)
// Wave = 16 rows x 64 cols, K=512 in 16 steps of 32.
// ---------------------------------------------------------------------------
__global__ __launch_bounds__(256) void k_project(
    const float* __restrict__ A, const float* __restrict__ Bm,
    const __hip_bfloat16* __restrict__ Rt,
    __hip_bfloat16* __restrict__ ra, __hip_bfloat16* __restrict__ rb,
    unsigned char* __restrict__ mask)
{
  const int t = threadIdx.x;
  const int w = t >> 6, lane = t & 63;
  const int m = lane & 15, quad = lane >> 4;
  const int blk = blockIdx.x;                 // 0..511; >=256 -> B half
  const bool isB = blk >= 256;
  const float* __restrict__ src = isB ? Bm : A;
  const int rowbase = ((isB ? blk - 256 : blk) * 4 + w) * 16;  // 16 rows / wave
  const float* __restrict__ xrow = src + (size_t)(rowbase + m) * EMB;

  f32x4 acc[4] = {{0.f,0.f,0.f,0.f},{0.f,0.f,0.f,0.f},
                  {0.f,0.f,0.f,0.f},{0.f,0.f,0.f,0.f}};
  float nzm = 0.f;

  #pragma unroll
  for (int kk = 0; kk < EMB; kk += 32) {
    float4 x0 = *reinterpret_cast<const float4*>(xrow + kk + quad * 8);
    float4 x1 = *reinterpret_cast<const float4*>(xrow + kk + quad * 8 + 4);

    nzm = fmaxf(nzm, fmaxf(fmaxf(fabsf(x0.x), fabsf(x0.y)),
                           fmaxf(fabsf(x0.z), fabsf(x0.w))));
    nzm = fmaxf(nzm, fmaxf(fmaxf(fabsf(x1.x), fabsf(x1.y)),
                           fmaxf(fabsf(x1.z), fabsf(x1.w))));

    union { bf16x8 v; __hip_bfloat16 h[8]; } af;
    af.h[0] = __float2bfloat16(x0.x); af.h[1] = __float2bfloat16(x0.y);
    af.h[2] = __float2bfloat16(x0.z); af.h[3] = __float2bfloat16(x0.w);
    af.h[4] = __float2bfloat16(x1.x); af.h[5] = __float2bfloat16(x1.y);
    af.h[6] = __float2bfloat16(x1.z); af.h[7] = __float2bfloat16(x1.w);

    #pragma unroll
    for (int nt = 0; nt < 4; ++nt) {
      bf16x8 bf = *reinterpret_cast<const bf16x8*>(
          Rt + (size_t)(nt * 16 + m) * EMB + kk + quad * 8);
      acc[nt] = __builtin_amdgcn_mfma_f32_16x16x32_bf16(af.v, bf, acc[nt], 0, 0, 0);
    }
  }

  const float scale = isB ? SCALE_B : SCALE_A;
  __hip_bfloat16* __restrict__ dst = isB ? rb : ra;
  #pragma unroll
  for (int nt = 0; nt < 4; ++nt) {
    #pragma unroll
    for (int i = 0; i < 4; ++i) {
      const int r = rowbase + quad * 4 + i;          // C/D row = quad*4+i
      dst[(size_t)r * RD + nt * 16 + m] = __float2bfloat16(acc[nt][i] * scale);
    }
  }

  float v = nzm;
  v = fmaxf(v, __shfl_xor(v, 16));
  v = fmaxf(v, __shfl_xor(v, 32));
  if (isB && lane < 16)
    mask[rowbase + lane] = (v == 0.f) ? 1 : 0;
}

// ---------------------------------------------------------------------------
// Kernel 2 v2: single GEMM pass, e-values held in VGPRs (32x4 = 128 regs).
// Pass 2 is a pure scaled store stream — no loads, no MFMA, no exp.
// ---------------------------------------------------------------------------
__global__ __launch_bounds__(256) void k_scores(
    const __hip_bfloat16* __restrict__ ra, const __hip_bfloat16* __restrict__ rb,
    const unsigned char* __restrict__ mask, const float* __restrict__ bptr,
    float* __restrict__ out)
{
  const int bz = blockIdx.y;
  const int row_base = blockIdx.x * 16;
  const int w = threadIdx.x >> 6, lane = threadIdx.x & 63;
  const int m = lane & 15, quad = lane >> 4;
  const float bias = bptr[0];

  const __hip_bfloat16* __restrict__ raB = ra + ((size_t)bz * K1 + row_base) * RD;
  const __hip_bfloat16* __restrict__ rbB = rb + (size_t)bz * K2 * RD;
  const unsigned char* __restrict__ mk = mask + bz * K2;

  // A frags: lane holds A[m=lane&15][k = quad*8 + j]  (two K=32 slabs)
  bf16x8 a0 = *reinterpret_cast<const bf16x8*>(raB + m * RD + quad * 8);
  bf16x8 a1 = *reinterpret_cast<const bf16x8*>(raB + m * RD + 32 + quad * 8);

  float e[32][4];                     // per-lane exp values, kept in VGPRs
  float sums[4] = {0.f, 0.f, 0.f, 0.f};

  // ---- pass 1: GEMM + exp, accumulate row sums, keep e in registers ----
  #pragma unroll
  for (int it = 0; it < 32; ++it) {
    const int tle = it * 4 + w;
    const int n = tle * 16 + m;
    bf16x8 b0 = *reinterpret_cast<const bf16x8*>(rbB + n * RD + quad * 8);
    bf16x8 b1 = *reinterpret_cast<const bf16x8*>(rbB + n * RD + 32 + quad * 8);
    f32x4 c = {0.f, 0.f, 0.f, 0.f};
    c = __builtin_amdgcn_mfma_f32_16x16x32_bf16(a0, b0, c, 0, 0, 0);
    c = __builtin_amdgcn_mfma_f32_16x16x32_bf16(a1, b1, c, 0, 0, 0);
    const bool msk = mk[n] != 0;
    #pragma unroll
    for (int i = 0; i < 4; ++i) {
      float v = msk ? 0.f : __expf(c[i] + bias);   // C/D: col=lane&15, row=quad*4+i
      e[it][i] = v;
      sums[i] += v;
    }
  }

  // reduce over the 16 lanes (col dimension) of each quad
  #pragma unroll
  for (int i = 0; i < 4; ++i) {
    float v = sums[i];
    v += __shfl_xor(v, 1);
    v += __shfl_xor(v, 2);
    v += __shfl_xor(v, 4);
    v += __shfl_xor(v, 8);
    sums[i] = v;
  }

  __shared__ float partial[4][16];
  __shared__ float rowinv[16];
  if ((lane & 15) == 0) {
    #pragma unroll
    for (int i = 0; i < 4; ++i) partial[w][quad * 4 + i] = sums[i];
  }
  __syncthreads();
  if (threadIdx.x < 16) {
    float tsum = partial[0][threadIdx.x] + partial[1][threadIdx.x] +
                 partial[2][threadIdx.x] + partial[3][threadIdx.x];
    rowinv[threadIdx.x] = 1.0f / tsum;
  }
  __syncthreads();

  float inv[4];
  #pragma unroll
  for (int i = 0; i < 4; ++i) inv[i] = rowinv[quad * 4 + i];

  // ---- pass 2: pure store stream, p = e * inv ----
  float* __restrict__ outB = out + ((size_t)bz * K1 + row_base) * K2;
  #pragma unroll
  for (int it = 0; it < 32; ++it) {
    const int n = (it * 4 + w) * 16 + m;
    #pragma unroll
    for (int i = 0; i < 4; ++i)
      outB[(size_t)(quad * 4 + i) * K2 + n] = e[it][i] * inv[i];
  }
}

extern "C" void kernel_launch(void* const* d_in, const int* in_sizes, int n_in,
                              void* d_out, int out_size, void* d_ws, size_t ws_size,
                              hipStream_t stream) {
  const float* A  = (const float*)d_in[0];   // (8, 2048, 512)
  const float* Bm = (const float*)d_in[1];   // (8, 2048, 512)
  const float* R  = (const float*)d_in[2];   // (512, 64)
  const float* bb = (const float*)d_in[3];   // (1,)
  float* out = (float*)d_out;                // (8, 2048, 2048)

  char* ws = (char*)d_ws;
  __hip_bfloat16* ra  = (__hip_bfloat16*)(ws);                         // 2 MB
  __hip_bfloat16* rb  = (__hip_bfloat16*)(ws + (((size_t)2) << 20));   // 2 MB
  __hip_bfloat16* Rt  = (__hip_bfloat16*)(ws + (((size_t)4) << 20));   // 64 KB
  unsigned char*  msk = (unsigned char*) (ws + (((size_t)4) << 20) + 65536); // 16 KB

  k_prep_rt<<<dim3(128), dim3(256), 0, stream>>>(R, Rt);
  k_project<<<dim3(512), dim3(256), 0, stream>>>(A, Bm, Rt, ra, rb, msk);
  k_scores <<<dim3(K1 / 16, NB), dim3(256), 0, stream>>>(ra, rb, msk, bb, out);
}

// Round 5
// 222.264 us; speedup vs baseline: 1.3400x; 1.0861x over previous
//
#include <hip/hip_runtime.h>
#include <hip/hip_bf16.h>

#define EMB 512
#define RD  64
#define NB  8
#define K1  2048
#define K2  2048

typedef short bf16x8 __attribute__((ext_vector_type(8)));  // 8 bf16 = 4 VGPRs
typedef float f32x4  __attribute__((ext_vector_type(4)));

// emb_scale = 1/sqrt(512); red_scale = 1/8 folded into ra
#define SCALE_B 0.04419417382415922f
#define SCALE_A 0.005524271728019902f

__device__ __forceinline__ float bf16lo_to_f(unsigned int u) {
  union { unsigned int u; float f; } c; c.u = u << 16; return c.f;
}
__device__ __forceinline__ float bf16hi_to_f(unsigned int u) {
  union { unsigned int u; float f; } c; c.u = u & 0xFFFF0000u; return c.f;
}
__device__ __forceinline__ unsigned short f_to_bf16u(float v) {
  union { __hip_bfloat16 h; unsigned short s; } c; c.h = __float2bfloat16(v); return c.s;
}

// ---------------------------------------------------------------------------
// Kernel 0: Rt[n][k] = bf16(R[k][n])  (64 x 512, 64 KB) — B-operand layout.
// Index over OUTPUT so the 2-B stores are contiguous; scattered reads hit L2.
// ---------------------------------------------------------------------------
__global__ __launch_bounds__(256) void k_prep_rt(
    const float* __restrict__ R, __hip_bfloat16* __restrict__ Rt)
{
  int idx = blockIdx.x * 256 + threadIdx.x;   // 32768 total
  int n = idx >> 9, k = idx & 511;            // coalesced write of Rt[n][k]
  Rt[idx] = __float2bfloat16(R[(size_t)k * RD + n]);
}

// ---------------------------------------------------------------------------
// Kernel 1: projection via bf16 MFMA, no LDS, explicit x-prefetch.
// Wave = 16 rows x 64 cols, K=512 in 16 steps of 32.
// ---------------------------------------------------------------------------
__global__ __launch_bounds__(256) void k_project(
    const float* __restrict__ A, const float* __restrict__ Bm,
    const __hip_bfloat16* __restrict__ Rt,
    __hip_bfloat16* __restrict__ ra, __hip_bfloat16* __restrict__ rb,
    unsigned char* __restrict__ mask)
{
  const int t = threadIdx.x;
  const int w = t >> 6, lane = t & 63;
  const int m = lane & 15, quad = lane >> 4;
  const int blk = blockIdx.x;                 // 0..511; >=256 -> B half
  const bool isB = blk >= 256;
  const float* __restrict__ src = isB ? Bm : A;
  const int rowbase = ((isB ? blk - 256 : blk) * 4 + w) * 16;  // 16 rows / wave
  const float4* __restrict__ xp =
      reinterpret_cast<const float4*>(src + (size_t)(rowbase + m) * EMB) + quad * 2;

  f32x4 acc[4] = {{0.f,0.f,0.f,0.f},{0.f,0.f,0.f,0.f},
                  {0.f,0.f,0.f,0.f},{0.f,0.f,0.f,0.f}};
  float nzm = 0.f;

  float4 x0 = xp[0], x1 = xp[1];              // step 0 in flight before loop

  #pragma unroll
  for (int s = 0; s < 16; ++s) {
    float4 p0, p1;                            // prefetch next step
    if (s < 15) { p0 = xp[(s + 1) * 8]; p1 = xp[(s + 1) * 8 + 1]; }

    nzm = fmaxf(nzm, fmaxf(fmaxf(fabsf(x0.x), fabsf(x0.y)),
                           fmaxf(fabsf(x0.z), fabsf(x0.w))));
    nzm = fmaxf(nzm, fmaxf(fmaxf(fabsf(x1.x), fabsf(x1.y)),
                           fmaxf(fabsf(x1.z), fabsf(x1.w))));

    union { bf16x8 v; __hip_bfloat16 h[8]; } af;
    af.h[0] = __float2bfloat16(x0.x); af.h[1] = __float2bfloat16(x0.y);
    af.h[2] = __float2bfloat16(x0.z); af.h[3] = __float2bfloat16(x0.w);
    af.h[4] = __float2bfloat16(x1.x); af.h[5] = __float2bfloat16(x1.y);
    af.h[6] = __float2bfloat16(x1.z); af.h[7] = __float2bfloat16(x1.w);

    const int kk = s * 32;
    #pragma unroll
    for (int nt = 0; nt < 4; ++nt) {
      bf16x8 bf = *reinterpret_cast<const bf16x8*>(
          Rt + (size_t)(nt * 16 + m) * EMB + kk + quad * 8);
      acc[nt] = __builtin_amdgcn_mfma_f32_16x16x32_bf16(af.v, bf, acc[nt], 0, 0, 0);
    }
    x0 = p0; x1 = p1;
  }

  const float scale = isB ? SCALE_B : SCALE_A;
  __hip_bfloat16* __restrict__ dst = isB ? rb : ra;
  #pragma unroll
  for (int nt = 0; nt < 4; ++nt) {
    #pragma unroll
    for (int i = 0; i < 4; ++i) {
      const int r = rowbase + quad * 4 + i;          // C/D row = quad*4+i
      dst[(size_t)r * RD + nt * 16 + m] = __float2bfloat16(acc[nt][i] * scale);
    }
  }

  float v = nzm;
  v = fmaxf(v, __shfl_xor(v, 16));
  v = fmaxf(v, __shfl_xor(v, 32));
  if (isB && lane < 16)
    mask[rowbase + lane] = (v == 0.f) ? 1 : 0;
}

// ---------------------------------------------------------------------------
// Kernel 2 v3: single GEMM pass; e-values packed 2-per-dword as bf16
// (64 VGPRs instead of 128 -> ~4 waves/SIMD). Pass 2 = pure store stream.
// ---------------------------------------------------------------------------
__global__ __launch_bounds__(256) void k_scores(
    const __hip_bfloat16* __restrict__ ra, const __hip_bfloat16* __restrict__ rb,
    const unsigned char* __restrict__ mask, const float* __restrict__ bptr,
    float* __restrict__ out)
{
  const int bz = blockIdx.y;
  const int row_base = blockIdx.x * 16;
  const int w = threadIdx.x >> 6, lane = threadIdx.x & 63;
  const int m = lane & 15, quad = lane >> 4;
  const float bias = bptr[0];

  const __hip_bfloat16* __restrict__ raB = ra + ((size_t)bz * K1 + row_base) * RD;
  const __hip_bfloat16* __restrict__ rbB = rb + (size_t)bz * K2 * RD;
  const unsigned char* __restrict__ mk = mask + bz * K2;

  // A frags: lane holds A[m=lane&15][k = quad*8 + j]  (two K=32 slabs)
  bf16x8 a0 = *reinterpret_cast<const bf16x8*>(raB + m * RD + quad * 8);
  bf16x8 a1 = *reinterpret_cast<const bf16x8*>(raB + m * RD + 32 + quad * 8);

  unsigned int epk[16][4];            // e as packed bf16 pairs (64 VGPRs)
  float sums[4] = {0.f, 0.f, 0.f, 0.f};

  // ---- pass 1: GEMM + exp; fp32 sums from unrounded e; pack e to bf16 ----
  #pragma unroll
  for (int it2 = 0; it2 < 16; ++it2) {
    const int n0 = (it2 * 8 + w) * 16 + m;          // tiles 2*it2 and 2*it2+1
    const int n1 = (it2 * 8 + 4 + w) * 16 + m;
    bf16x8 b00 = *reinterpret_cast<const bf16x8*>(rbB + n0 * RD + quad * 8);
    bf16x8 b01 = *reinterpret_cast<const bf16x8*>(rbB + n0 * RD + 32 + quad * 8);
    bf16x8 b10 = *reinterpret_cast<const bf16x8*>(rbB + n1 * RD + quad * 8);
    bf16x8 b11 = *reinterpret_cast<const bf16x8*>(rbB + n1 * RD + 32 + quad * 8);
    f32x4 c0 = {0.f, 0.f, 0.f, 0.f}, c1 = {0.f, 0.f, 0.f, 0.f};
    c0 = __builtin_amdgcn_mfma_f32_16x16x32_bf16(a0, b00, c0, 0, 0, 0);
    c1 = __builtin_amdgcn_mfma_f32_16x16x32_bf16(a0, b10, c1, 0, 0, 0);
    c0 = __builtin_amdgcn_mfma_f32_16x16x32_bf16(a1, b01, c0, 0, 0, 0);
    c1 = __builtin_amdgcn_mfma_f32_16x16x32_bf16(a1, b11, c1, 0, 0, 0);
    const bool k0 = mk[n0] != 0, k1 = mk[n1] != 0;
    #pragma unroll
    for (int i = 0; i < 4; ++i) {
      float v0 = k0 ? 0.f : __expf(c0[i] + bias);   // C/D: col=m, row=quad*4+i
      float v1 = k1 ? 0.f : __expf(c1[i] + bias);
      sums[i] += v0 + v1;
      epk[it2][i] = (unsigned int)f_to_bf16u(v0) |
                    ((unsigned int)f_to_bf16u(v1) << 16);
    }
  }

  // reduce over the 16 lanes (col dimension) of each quad
  #pragma unroll
  for (int i = 0; i < 4; ++i) {
    float v = sums[i];
    v += __shfl_xor(v, 1);
    v += __shfl_xor(v, 2);
    v += __shfl_xor(v, 4);
    v += __shfl_xor(v, 8);
    sums[i] = v;
  }

  __shared__ float partial[4][16];
  __shared__ float rowinv[16];
  if ((lane & 15) == 0) {
    #pragma unroll
    for (int i = 0; i < 4; ++i) partial[w][quad * 4 + i] = sums[i];
  }
  __syncthreads();
  if (threadIdx.x < 16) {
    float tsum = partial[0][threadIdx.x] + partial[1][threadIdx.x] +
                 partial[2][threadIdx.x] + partial[3][threadIdx.x];
    rowinv[threadIdx.x] = 1.0f / tsum;
  }
  __syncthreads();

  float inv[4];
  #pragma unroll
  for (int i = 0; i < 4; ++i) inv[i] = rowinv[quad * 4 + i];

  // ---- pass 2: pure store stream, p = e * inv ----
  float* __restrict__ outB = out + ((size_t)bz * K1 + row_base) * K2;
  #pragma unroll
  for (int it2 = 0; it2 < 16; ++it2) {
    const int n0 = (it2 * 8 + w) * 16 + m;
    const int n1 = (it2 * 8 + 4 + w) * 16 + m;
    #pragma unroll
    for (int i = 0; i < 4; ++i) {
      const size_t rowoff = (size_t)(quad * 4 + i) * K2;
      outB[rowoff + n0] = bf16lo_to_f(epk[it2][i]) * inv[i];
      outB[rowoff + n1] = bf16hi_to_f(epk[it2][i]) * inv[i];
    }
  }
}

extern "C" void kernel_launch(void* const* d_in, const int* in_sizes, int n_in,
                              void* d_out, int out_size, void* d_ws, size_t ws_size,
                              hipStream_t stream) {
  const float* A  = (const float*)d_in[0];   // (8, 2048, 512)
  const float* Bm = (const float*)d_in[1];   // (8, 2048, 512)
  const float* R  = (const float*)d_in[2];   // (512, 64)
  const float* bb = (const float*)d_in[3];   // (1,)
  float* out = (float*)d_out;                // (8, 2048, 2048)

  char* ws = (char*)d_ws;
  __hip_bfloat16* ra  = (__hip_bfloat16*)(ws);                         // 2 MB
  __hip_bfloat16* rb  = (__hip_bfloat16*)(ws + (((size_t)2) << 20));   // 2 MB
  __hip_bfloat16* Rt  = (__hip_bfloat16*)(ws + (((size_t)4) << 20));   // 64 KB
  unsigned char*  msk = (unsigned char*) (ws + (((size_t)4) << 20) + 65536); // 16 KB

  k_prep_rt<<<dim3(128), dim3(256), 0, stream>>>(R, Rt);
  k_project<<<dim3(512), dim3(256), 0, stream>>>(A, Bm, Rt, ra, rb, msk);
  k_scores <<<dim3(K1 / 16, NB), dim3(256), 0, stream>>>(ra, rb, msk, bb, out);
}